// Round 1
// baseline (289.260 us; speedup 1.0000x reference)
//
#include <hip/hip_runtime.h>

// Problem constants (fixed by setup_inputs: B=32, N=128, D=4096, s=128).
// s == N1 == N2 => self_errors = e1, factor_errors = e2, M = 128.
constexpr int B  = 32;
constexpr int N  = 128;          // N1 = N2 = s = M
constexpr int D  = 4096;
constexpr int DV = D / 4;        // float4 columns per row = 1024
constexpr int COLS   = 64;       // float4 columns handled per block
constexpr int CHUNKS = 4;        // n-chunks, one per wave
constexpr int NPC    = N / CHUNKS;     // 32 n per chunk
constexpr int TPB    = COLS * CHUNKS;  // 256 threads
constexpr int TILES  = DV / COLS;      // 16 tiles per b

__device__ __forceinline__ float4 f4add(float4 a, float4 b) {
    return make_float4(a.x + b.x, a.y + b.y, a.z + b.z, a.w + b.w);
}

__global__ __launch_bounds__(TPB) void relaxed_prod_kernel(
    const float* __restrict__ h1,   // curr_head    (B,D)
    const float* __restrict__ e1,   // curr_errors  (B,N,D)  = self
    const float* __restrict__ h2,   // curr_head_2  (B,D)
    const float* __restrict__ e2,   // curr_errors_2(B,N,D)  = factor
    const float* __restrict__ adv,  // adv_errors   (B,N,D)
    float* __restrict__ out)        // [B*D new_head][B*2N*D new_errors]
{
    const int lane  = threadIdx.x & (COLS - 1);
    const int chunk = threadIdx.x / COLS;          // == wave index
    const int tile  = blockIdx.x % TILES;
    const int b     = blockIdx.x / TILES;
    const int col   = tile * COLS + lane;          // float4 column
    const long d0   = (long)col * 4;               // float column

    const float4* e1p  = (const float4*)(e1  + (long)b * N * D + d0);
    const float4* e2p  = (const float4*)(e2  + (long)b * N * D + d0);
    const float4* advp = (const float4*)(adv + (long)b * N * D + d0);
    float4* lin_out = (float4*)(out + (long)B * D + (long)b * (2 * N) * D + d0);
    float4* adv_out = lin_out + (long)N * DV;

    const float4 vh1 = *(const float4*)(h1 + (long)b * D + d0);
    const float4 vh2 = *(const float4*)(h2 + (long)b * D + d0);

    float4 sq  = make_float4(0.f, 0.f, 0.f, 0.f);  // sum e1*e2
    float4 sa  = make_float4(0.f, 0.f, 0.f, 0.f);  // sum |e1|
    float4 saq = make_float4(0.f, 0.f, 0.f, 0.f);  // sum |e1*e2|

    const int n0 = chunk * NPC;
#pragma unroll 8
    for (int i = 0; i < NPC; ++i) {
        const long off = (long)(n0 + i) * DV;
        float4 a = e1p[off];
        float4 c = e2p[off];
        float4 lin;
        lin.x = vh1.x * c.x + vh2.x * a.x;
        lin.y = vh1.y * c.y + vh2.y * a.y;
        lin.z = vh1.z * c.z + vh2.z * a.z;
        lin.w = vh1.w * c.w + vh2.w * a.w;
        lin_out[off] = lin;
        float4 q = make_float4(a.x * c.x, a.y * c.y, a.z * c.z, a.w * c.w);
        sq  = f4add(sq, q);
        sa.x += fabsf(a.x); sa.y += fabsf(a.y); sa.z += fabsf(a.z); sa.w += fabsf(a.w);
        saq.x += fabsf(q.x); saq.y += fabsf(q.y); saq.z += fabsf(q.z); saq.w += fabsf(q.w);
    }

    __shared__ float4 s_q [CHUNKS][COLS];
    __shared__ float4 s_a [CHUNKS][COLS];
    __shared__ float4 s_aq[CHUNKS][COLS];
    __shared__ float4 s_qe[COLS];
    s_q [chunk][lane] = sq;
    s_a [chunk][lane] = sa;
    s_aq[chunk][lane] = saq;
    __syncthreads();

    if (chunk == 0) {
        float4 tq  = f4add(f4add(s_q [0][lane], s_q [1][lane]),
                           f4add(s_q [2][lane], s_q [3][lane]));
        float4 ta  = f4add(f4add(s_a [0][lane], s_a [1][lane]),
                           f4add(s_a [2][lane], s_a [3][lane]));
        float4 taq = f4add(f4add(s_aq[0][lane], s_aq[1][lane]),
                           f4add(s_aq[2][lane], s_aq[3][lane]));
        float4 qe;
        qe.x = ta.x * ta.x - 0.5f * taq.x;
        qe.y = ta.y * ta.y - 0.5f * taq.y;
        qe.z = ta.z * ta.z - 0.5f * taq.z;
        qe.w = ta.w * ta.w - 0.5f * taq.w;
        float4 nh;
        nh.x = vh1.x * vh2.x + 0.5f * tq.x;
        nh.y = vh1.y * vh2.y + 0.5f * tq.y;
        nh.z = vh1.z * vh2.z + 0.5f * tq.z;
        nh.w = vh1.w * vh2.w + 0.5f * tq.w;
        *(float4*)(out + (long)b * D + d0) = nh;
        s_qe[lane] = qe;
    }
    __syncthreads();

    const float4 qe = s_qe[lane];
#pragma unroll 8
    for (int i = 0; i < NPC; ++i) {
        const long off = (long)(n0 + i) * DV;
        float4 v = advp[off];
        float4 r = make_float4(qe.x * v.x, qe.y * v.y, qe.z * v.z, qe.w * v.w);
        adv_out[off] = r;
    }
}

extern "C" void kernel_launch(void* const* d_in, const int* in_sizes, int n_in,
                              void* d_out, int out_size, void* d_ws, size_t ws_size,
                              hipStream_t stream) {
    const float* h1  = (const float*)d_in[0];
    const float* e1  = (const float*)d_in[1];
    const float* h2  = (const float*)d_in[2];
    const float* e2  = (const float*)d_in[3];
    const float* adv = (const float*)d_in[4];
    // d_in[5] = shared_errors (int) — fixed at 128 = N1 = N2 by setup_inputs.
    float* out = (float*)d_out;

    dim3 grid(B * TILES);   // 512 blocks
    dim3 block(TPB);        // 256 threads
    relaxed_prod_kernel<<<grid, block, 0, stream>>>(h1, e1, h2, e2, adv, out);
}

// Round 2
// 288.725 us; speedup vs baseline: 1.0019x; 1.0019x over previous
//
#include <hip/hip_runtime.h>

// Problem constants (fixed by setup_inputs: B=32, N=128, D=4096, s=128).
// s == N1 == N2 => self_errors = e1, factor_errors = e2, M = 128.
constexpr int B  = 32;
constexpr int N  = 128;          // N1 = N2 = s = M
constexpr int D  = 4096;
constexpr int DV = D / 4;        // float4 columns per row = 1024
constexpr int COLS   = 64;       // float4 columns per block == wave width (1 KiB coalesced)
constexpr int CHUNKS = 16;       // n-chunks, one per wave -> 16 waves/block
constexpr int NPC    = N / CHUNKS;     // 8 n per chunk (fully unrolled)
constexpr int TPB    = COLS * CHUNKS;  // 1024 threads = 16 waves
constexpr int TILES  = DV / COLS;      // 16 tiles per b -> grid 512 = 2 blocks/CU
// Occupancy: 2 blocks/CU x 16 waves = 32 waves/CU (HW max). LDS 49 KiB/block.

__device__ __forceinline__ float4 f4add(float4 a, float4 b) {
    return make_float4(a.x + b.x, a.y + b.y, a.z + b.z, a.w + b.w);
}

__global__ __launch_bounds__(TPB) void relaxed_prod_kernel(
    const float* __restrict__ h1,   // curr_head    (B,D)
    const float* __restrict__ e1,   // curr_errors  (B,N,D)  = self
    const float* __restrict__ h2,   // curr_head_2  (B,D)
    const float* __restrict__ e2,   // curr_errors_2(B,N,D)  = factor
    const float* __restrict__ adv,  // adv_errors   (B,N,D)
    float* __restrict__ out)        // [B*D new_head][B*2N*D new_errors]
{
    const int lane  = threadIdx.x & (COLS - 1);
    const int chunk = threadIdx.x / COLS;          // == wave index (0..15)
    const int tile  = blockIdx.x % TILES;
    const int b     = blockIdx.x / TILES;
    const int col   = tile * COLS + lane;          // float4 column
    const long d0   = (long)col * 4;               // float column

    const float4* e1p  = (const float4*)(e1  + (long)b * N * D + d0);
    const float4* e2p  = (const float4*)(e2  + (long)b * N * D + d0);
    const float4* advp = (const float4*)(adv + (long)b * N * D + d0);
    float4* lin_out = (float4*)(out + (long)B * D + (long)b * (2 * N) * D + d0);
    float4* adv_out = lin_out + (long)N * DV;

    const float4 vh1 = *(const float4*)(h1 + (long)b * D + d0);
    const float4 vh2 = *(const float4*)(h2 + (long)b * D + d0);

    float4 sq  = make_float4(0.f, 0.f, 0.f, 0.f);  // sum e1*e2
    float4 sa  = make_float4(0.f, 0.f, 0.f, 0.f);  // sum |e1|
    float4 saq = make_float4(0.f, 0.f, 0.f, 0.f);  // sum |e1*e2|

    const int n0 = chunk * NPC;
#pragma unroll
    for (int i = 0; i < NPC; ++i) {
        const long off = (long)(n0 + i) * DV;
        float4 a = e1p[off];
        float4 c = e2p[off];
        float4 lin;
        lin.x = vh1.x * c.x + vh2.x * a.x;
        lin.y = vh1.y * c.y + vh2.y * a.y;
        lin.z = vh1.z * c.z + vh2.z * a.z;
        lin.w = vh1.w * c.w + vh2.w * a.w;
        lin_out[off] = lin;
        float4 q = make_float4(a.x * c.x, a.y * c.y, a.z * c.z, a.w * c.w);
        sq  = f4add(sq, q);
        sa.x += fabsf(a.x); sa.y += fabsf(a.y); sa.z += fabsf(a.z); sa.w += fabsf(a.w);
        saq.x += fabsf(q.x); saq.y += fabsf(q.y); saq.z += fabsf(q.z); saq.w += fabsf(q.w);
    }

    __shared__ float4 s_q [CHUNKS][COLS];
    __shared__ float4 s_a [CHUNKS][COLS];
    __shared__ float4 s_aq[CHUNKS][COLS];
    __shared__ float4 s_qe[COLS];
    s_q [chunk][lane] = sq;
    s_a [chunk][lane] = sa;
    s_aq[chunk][lane] = saq;
    __syncthreads();

    if (chunk == 0) {
        float4 tq  = s_q [0][lane];
        float4 ta  = s_a [0][lane];
        float4 taq = s_aq[0][lane];
#pragma unroll
        for (int c = 1; c < CHUNKS; ++c) {
            tq  = f4add(tq,  s_q [c][lane]);
            ta  = f4add(ta,  s_a [c][lane]);
            taq = f4add(taq, s_aq[c][lane]);
        }
        float4 qe;
        qe.x = ta.x * ta.x - 0.5f * taq.x;
        qe.y = ta.y * ta.y - 0.5f * taq.y;
        qe.z = ta.z * ta.z - 0.5f * taq.z;
        qe.w = ta.w * ta.w - 0.5f * taq.w;
        float4 nh;
        nh.x = vh1.x * vh2.x + 0.5f * tq.x;
        nh.y = vh1.y * vh2.y + 0.5f * tq.y;
        nh.z = vh1.z * vh2.z + 0.5f * tq.z;
        nh.w = vh1.w * vh2.w + 0.5f * tq.w;
        *(float4*)(out + (long)b * D + d0) = nh;
        s_qe[lane] = qe;
    }
    __syncthreads();

    const float4 qe = s_qe[lane];
#pragma unroll
    for (int i = 0; i < NPC; ++i) {
        const long off = (long)(n0 + i) * DV;
        float4 v = advp[off];
        float4 r = make_float4(qe.x * v.x, qe.y * v.y, qe.z * v.z, qe.w * v.w);
        adv_out[off] = r;
    }
}

extern "C" void kernel_launch(void* const* d_in, const int* in_sizes, int n_in,
                              void* d_out, int out_size, void* d_ws, size_t ws_size,
                              hipStream_t stream) {
    const float* h1  = (const float*)d_in[0];
    const float* e1  = (const float*)d_in[1];
    const float* h2  = (const float*)d_in[2];
    const float* e2  = (const float*)d_in[3];
    const float* adv = (const float*)d_in[4];
    // d_in[5] = shared_errors (int) — fixed at 128 = N1 = N2 by setup_inputs.
    float* out = (float*)d_out;

    dim3 grid(B * TILES);   // 512 blocks, 2 per CU
    dim3 block(TPB);        // 1024 threads = 16 waves
    relaxed_prod_kernel<<<grid, block, 0, stream>>>(h1, e1, h2, e2, adv, out);
}